// Round 6
// baseline (305.567 us; speedup 1.0000x reference)
//
#include <hip/hip_runtime.h>
#include <hip/hip_cooperative_groups.h>
#include <math.h>

namespace cg = cooperative_groups;

#define IMG_H 512
#define IMG_W 512
#define NIMG 32
#define RB_W 552        // rowbuf padded width; cmax x -> index 20+x, halo [0..19] & [532..551]
#define T5_W 544        // tmp5 padded width (542 used, 2 tail slots never read)
#define YC2 32          // output rows per tile in phase 2
#define GRID_F 1024     // fused grid: exactly 4 blocks/CU co-resident on 256 CUs

// ---- win5: tmp5[4q+d] = max(rowbuf[4q+3+d .. 4q+7+d]), d=0..3 (3 aligned b128 reads)
#define WIN5_TASK(rb, tmp5row, q)                                                    \
    {                                                                                \
        float4 w0 = (rb)[(q)], w1 = (rb)[(q) + 1], w2 = (rb)[(q) + 2];               \
        float f3 = w0.w, f4 = w1.x, f5 = w1.y, f6 = w1.z, f7 = w1.w;                 \
        float f8 = w2.x, f9 = w2.y, f10 = w2.z;                                      \
        float a34 = fmaxf(f3, f4), a45 = fmaxf(f4, f5), a56 = fmaxf(f5, f6);         \
        float a67 = fmaxf(f6, f7), a78 = fmaxf(f7, f8), a89 = fmaxf(f8, f9);         \
        float4 o;                                                                    \
        o.x = fmaxf(fmaxf(a34, a56), f7);                                            \
        o.y = fmaxf(fmaxf(a45, a67), f8);                                            \
        o.z = fmaxf(fmaxf(a56, a78), f9);                                            \
        o.w = fmaxf(fmaxf(a67, a89), f10);                                           \
        *(float4*)&(tmp5row)[4 * (q)] = o;                                           \
    }
// ---- win35: out[4q+d] = max_k tmp5[4q+d+5k], k=0..6 (9 aligned b128 reads)
#define WIN35_TASK(t5, q, orow)                                                      \
    {                                                                                \
        float wf[36];                                                                \
        _Pragma("unroll")                                                            \
        for (int k = 0; k < 9; ++k) {                                                \
            float4 t = (t5)[(q) + k];                                                \
            wf[4 * k + 0] = t.x; wf[4 * k + 1] = t.y;                                \
            wf[4 * k + 2] = t.z; wf[4 * k + 3] = t.w;                                \
        }                                                                            \
        float4 o;                                                                    \
        o.x = fmaxf(fmaxf(fmaxf(wf[0], wf[5]), fmaxf(wf[10], wf[15])),               \
                    fmaxf(fmaxf(wf[20], wf[25]), wf[30]));                           \
        o.y = fmaxf(fmaxf(fmaxf(wf[1], wf[6]), fmaxf(wf[11], wf[16])),               \
                    fmaxf(fmaxf(wf[21], wf[26]), wf[31]));                           \
        o.z = fmaxf(fmaxf(fmaxf(wf[2], wf[7]), fmaxf(wf[12], wf[17])),               \
                    fmaxf(fmaxf(wf[22], wf[27]), wf[32]));                           \
        o.w = fmaxf(fmaxf(fmaxf(wf[3], wf[8]), fmaxf(wf[13], wf[18])),               \
                    fmaxf(fmaxf(wf[23], wf[28]), wf[33]));                           \
        *(float4*)&(orow)[4 * (q)] = o;                                              \
    }

// ---------------- Phase 1 row body (R4's barrier-free wave-per-row, verbatim) --------
__device__ __forceinline__ void p1_row(const float* __restrict__ img,
                                       float* __restrict__ rowmax,
                                       int n, int y, int lane,
                                       float* rowbufr, float* tmp5r) {
    const float4* imgr = (const float4*)(img + ((size_t)n * 3 * IMG_H + y) * IMG_W);
    float4 a0 = imgr[lane],          a1 = imgr[lane + 64];
    float4 b0 = imgr[65536 + lane],  b1 = imgr[65536 + lane + 64];
    float4 c0 = imgr[131072 + lane], c1 = imgr[131072 + lane + 64];
    float4 m0, m1;
    m0.x = 1.0f - fminf(a0.x, fminf(b0.x, c0.x));
    m0.y = 1.0f - fminf(a0.y, fminf(b0.y, c0.y));
    m0.z = 1.0f - fminf(a0.z, fminf(b0.z, c0.z));
    m0.w = 1.0f - fminf(a0.w, fminf(b0.w, c0.w));
    m1.x = 1.0f - fminf(a1.x, fminf(b1.x, c1.x));
    m1.y = 1.0f - fminf(a1.y, fminf(b1.y, c1.y));
    m1.z = 1.0f - fminf(a1.z, fminf(b1.z, c1.z));
    m1.w = 1.0f - fminf(a1.w, fminf(b1.w, c1.w));
    *(float4*)&rowbufr[20 + 4 * lane] = m0;
    *(float4*)&rowbufr[20 + 4 * (lane + 64)] = m1;
    // within-wave LDS visibility (rule #18: lgkmcnt + sched_barrier)
    asm volatile("s_waitcnt lgkmcnt(0)" ::: "memory");
    __builtin_amdgcn_sched_barrier(0);

    const float4* rb = (const float4*)rowbufr;         // 16B-aligned (552*4B row)
    WIN5_TASK(rb, tmp5r, lane)
    WIN5_TASK(rb, tmp5r, lane + 64)
    if (lane < 8) WIN5_TASK(rb, tmp5r, lane + 128)     // 64+64+8 = 136 tasks
    asm volatile("s_waitcnt lgkmcnt(0)" ::: "memory");
    __builtin_amdgcn_sched_barrier(0);

    const float4* t5 = (const float4*)tmp5r;           // 16B-aligned (544*4B row)
    float* orow = rowmax + ((size_t)n * IMG_H + y) * IMG_W;
    WIN35_TASK(t5, lane, orow)
    WIN35_TASK(t5, lane + 64, orow)
}

// ---------------- Phase 2 tile body (R2's register-ring colmax, verbatim) ------------
__device__ __forceinline__ void p2_tile(const float* __restrict__ rowmax,
                                        float* __restrict__ out,
                                        int b, float* wsum) {
    const int yt = b & 15;
    const int n = b >> 4;
    const int x0 = (int)threadIdx.x * 2;
    const int y0 = yt * YC2;
    const float2* col = (const float2*)(rowmax + (size_t)n * (IMG_H * IMG_W) + x0);

    float G0[5][6], G1[5][6];
    #pragma unroll
    for (int p = 0; p < 5; ++p)
        #pragma unroll
        for (int k = 0; k < 6; ++k) { G0[p][k] = -INFINITY; G1[p][k] = -INFINITY; }

    float a1, a2, a3, a4, b1, b2, b3, b4, s = 0.0f;
    {
        const int gy = y0 - 17;
        float2 v0 = ((unsigned)(gy + 0) < IMG_H) ? col[(size_t)(gy + 0) * (IMG_W / 2)]
                                                 : make_float2(-INFINITY, -INFINITY);
        float2 v1 = ((unsigned)(gy + 1) < IMG_H) ? col[(size_t)(gy + 1) * (IMG_W / 2)]
                                                 : make_float2(-INFINITY, -INFINITY);
        float2 v2 = ((unsigned)(gy + 2) < IMG_H) ? col[(size_t)(gy + 2) * (IMG_W / 2)]
                                                 : make_float2(-INFINITY, -INFINITY);
        float2 v3 = ((unsigned)(gy + 3) < IMG_H) ? col[(size_t)(gy + 3) * (IMG_W / 2)]
                                                 : make_float2(-INFINITY, -INFINITY);
        a1 = v0.x; a2 = v1.x; a3 = v2.x; a4 = v3.x;
        b1 = v0.y; b2 = v1.y; b3 = v2.y; b4 = v3.y;
    }

#define PUSH(P, J, DO_OUT)                                                              \
    {                                                                                   \
        const int gy_ = y0 - 13 + (J);                                                  \
        float2 v_ = ((unsigned)gy_ < IMG_H) ? col[(size_t)gy_ * (IMG_W / 2)]            \
                                            : make_float2(-INFINITY, -INFINITY);        \
        float gA_ = fmaxf(fmaxf(fmaxf(a1, a2), fmaxf(a3, a4)), v_.x);                   \
        float gB_ = fmaxf(fmaxf(fmaxf(b1, b2), fmaxf(b3, b4)), v_.y);                   \
        a1 = a2; a2 = a3; a3 = a4; a4 = v_.x;                                           \
        b1 = b2; b2 = b3; b3 = b4; b4 = v_.y;                                           \
        if (DO_OUT) {                                                                   \
            float oA_ = fmaxf(fmaxf(fmaxf(G0[P][0], G0[P][1]), fmaxf(G0[P][2], G0[P][3])), \
                              fmaxf(fmaxf(G0[P][4], G0[P][5]), gA_));                   \
            float oB_ = fmaxf(fmaxf(fmaxf(G1[P][0], G1[P][1]), fmaxf(G1[P][2], G1[P][3])), \
                              fmaxf(fmaxf(G1[P][4], G1[P][5]), gB_));                   \
            s += fabsf(oA_) + fabsf(oB_);                                               \
        }                                                                               \
        G0[P][0] = G0[P][1]; G0[P][1] = G0[P][2]; G0[P][2] = G0[P][3];                  \
        G0[P][3] = G0[P][4]; G0[P][4] = G0[P][5]; G0[P][5] = gA_;                       \
        G1[P][0] = G1[P][1]; G1[P][1] = G1[P][2]; G1[P][2] = G1[P][3];                  \
        G1[P][3] = G1[P][4]; G1[P][4] = G1[P][5]; G1[P][5] = gB_;                       \
    }
    #pragma unroll
    for (int g5 = 0; g5 < 6; ++g5) {
        const int j0 = 5 * g5;
        PUSH(0, j0 + 0, 0) PUSH(1, j0 + 1, 0) PUSH(2, j0 + 2, 0)
        PUSH(3, j0 + 3, 0) PUSH(4, j0 + 4, 0)
    }
    #pragma unroll
    for (int g5 = 6; g5 < 12; ++g5) {
        const int j0 = 5 * g5;
        PUSH(0, j0 + 0, 1) PUSH(1, j0 + 1, 1) PUSH(2, j0 + 2, 1)
        PUSH(3, j0 + 3, 1) PUSH(4, j0 + 4, 1)
    }
    PUSH(0, 60, 1)
    PUSH(1, 61, 1)
#undef PUSH

    #pragma unroll
    for (int off = 32; off > 0; off >>= 1) s += __shfl_down(s, off);
    const int lane = (int)threadIdx.x & 63, wv = (int)threadIdx.x >> 6;
    if (lane == 0) wsum[wv] = s;
    __syncthreads();
    if (threadIdx.x == 0) {
        float t = wsum[0] + wsum[1] + wsum[2] + wsum[3];
        atomicAdd(out, t * (1.0f / ((float)NIMG * IMG_H * IMG_W)));
    }
}

// ---------------- Fused cooperative kernel: phase1 (x4 grid-stride) -> grid.sync -> phase2
__global__ __launch_bounds__(256, 4) void dc_fused(const float* __restrict__ img,
                                                   float* __restrict__ rowmax,
                                                   float* __restrict__ out) {
    __shared__ __align__(16) float rowbuf[4][RB_W];
    __shared__ __align__(16) float tmp5[4][T5_W];
    __shared__ float wsum[4];
    const int tid = (int)threadIdx.x;
    const int lane = tid & 63;
    const int wv = tid >> 6;

    // halo pads written once; fill never overwrites them, valid for all 4 iterations
    if (lane < 40) {
        int idx = (lane < 20) ? lane : (512 + lane);   // [0,20) and [532,552)
        rowbuf[wv][idx] = -INFINITY;
    }
    #pragma unroll 1
    for (int k = 0; k < 4; ++k) {
        const int T = (int)blockIdx.x + GRID_F * k;    // row-tile 0..4095
        const int n = T >> 7;
        const int y = ((T & 127) << 2) + wv;
        p1_row(img, rowmax, n, y, lane, &rowbuf[wv][0], &tmp5[wv][0]);
        // next iteration's rowbuf writes are ordered after this iteration's LDS ops by
        // the lgkmcnt(0) drain at the top of p1_row's win5 (drains reads AND writes).
    }

    cg::this_grid().sync();                            // all rowmax rows visible

    if (blockIdx.x < NIMG * 16) p2_tile(rowmax, out, (int)blockIdx.x, wsum);
}

// ---------------- Fallback path: proven R4 two-kernel structure ----------------------
__global__ __launch_bounds__(256) void dc_rowmax(const float* __restrict__ img,
                                                 float* __restrict__ rowmax) {
    __shared__ __align__(16) float rowbuf[4][RB_W];
    __shared__ __align__(16) float tmp5[4][T5_W];
    const int b = blockIdx.x;            // n*128 + ytile
    const int n = b >> 7;
    const int lane = (int)threadIdx.x & 63;
    const int wv = (int)threadIdx.x >> 6;
    const int y = (b & 127) * 4 + wv;
    if (lane < 40) {
        int idx = (lane < 20) ? lane : (512 + lane);
        rowbuf[wv][idx] = -INFINITY;
    }
    p1_row(img, rowmax, n, y, lane, &rowbuf[wv][0], &tmp5[wv][0]);
}

__global__ __launch_bounds__(256) void dc_colmax(const float* __restrict__ rowmax,
                                                 float* __restrict__ out) {
    __shared__ float wsum[4];
    p2_tile(rowmax, out, (int)blockIdx.x, wsum);
}

extern "C" void kernel_launch(void* const* d_in, const int* in_sizes, int n_in,
                              void* d_out, int out_size, void* d_ws, size_t ws_size,
                              hipStream_t stream) {
    const float* img = (const float*)d_in[0];
    float* out = (float*)d_out;
    float* rowmax = (float*)d_ws;    // 32*512*512 floats = 33.5 MB scratch

    hipMemsetAsync(d_out, 0, sizeof(float), stream);
    void* kargs[] = { (void*)&img, (void*)&rowmax, (void*)&out };
    hipError_t e = hipLaunchCooperativeKernel((const void*)dc_fused, dim3(GRID_F),
                                              dim3(256), kargs, 0, stream);
    if (e != hipSuccess) {
        // capture-safe fallback: proven R4 two-kernel path
        dc_rowmax<<<NIMG * (IMG_H / 4), 256, 0, stream>>>(img, rowmax);
        dc_colmax<<<NIMG * 16, 256, 0, stream>>>(rowmax, out);
    }
}

// Round 7
// 161.418 us; speedup vs baseline: 1.8930x; 1.8930x over previous
//
#include <hip/hip_runtime.h>
#include <math.h>

#define IMG_H 512
#define IMG_W 512
#define NIMG 32
#define R_ROWS 4        // rows per block in pass 1 (one row per wave, 4 waves)
#define RB_W 552        // rowbuf padded width; cmax x -> index 20+x, halo [0..19] & [532..551]
#define T5_W 544        // tmp5 padded width (542 used, 2 tail slots never read)
#define YC2 32          // output rows per block in pass 2

// ---------------- Pass 1: cmax + horizontal win35, BARRIER-FREE (wave-per-row) --------
// Each wave owns one image row end-to-end: fill -> win5 -> win35. Cross-lane LDS data
// flow is within-wave only, so __syncthreads() is replaced by per-wave
// s_waitcnt lgkmcnt(0) (asm, "memory" clobber) — no s_barrier, no collective vmcnt(0)
// drain; the 32 waves/CU become independent row-pipelines.
// [R4 = best measured config, 161.06 us. R5 (2-row ILP pipeline) and R6 (cooperative
//  fusion) both regressed: ILP raised VGPR and cut TLP; grid.sync cost >> launch gap.]
__global__ __launch_bounds__(256) void dc_rowmax(const float* __restrict__ img,
                                                 float* __restrict__ rowmax) {
    __shared__ float rowbuf[R_ROWS][RB_W];
    __shared__ float tmp5[R_ROWS][T5_W];
    const int b = blockIdx.x;            // n*128 + ytile
    const int n = b >> 7;
    const int y0 = (b & 127) * R_ROWS;
    const int tid = (int)threadIdx.x;
    const int lane = tid & 63;
    const int wv = tid >> 6;             // wave -> row
    const int y = y0 + wv;

    // halo: lanes 0..39 write the 40 pad cells of this wave's row
    if (lane < 40) {
        int idx = (lane < 20) ? lane : (512 + lane);   // [0,20) and [532,552)
        rowbuf[wv][idx] = -INFINITY;
    }
    // fill: 128 float4 positions per row over 64 lanes (2 each)
    const float4* imgr = (const float4*)(img + ((size_t)n * 3 * IMG_H + y) * IMG_W);
    #pragma unroll
    for (int i = 0; i < 2; ++i) {
        int xq = lane + 64 * i;
        float4 a = imgr[xq];
        float4 b4 = imgr[65536 + xq];    // + H*W/4 (next channel)
        float4 c4 = imgr[131072 + xq];   // + 2*H*W/4
        float4 m;
        m.x = 1.0f - fminf(a.x, fminf(b4.x, c4.x));
        m.y = 1.0f - fminf(a.y, fminf(b4.y, c4.y));
        m.z = 1.0f - fminf(a.z, fminf(b4.z, c4.z));
        m.w = 1.0f - fminf(a.w, fminf(b4.w, c4.w));
        *(float4*)&rowbuf[wv][20 + 4 * xq] = m;       // 16B-aligned
    }
    // within-wave LDS visibility: all this wave's ds_writes retired before any ds_read
    asm volatile("s_waitcnt lgkmcnt(0)" ::: "memory");
    __builtin_amdgcn_sched_barrier(0);

    // win5: tmp5[4q+d] = max(rowbuf[4q+3+d .. 4q+7+d]); 136 quad-tasks per row
    const float4* rb = (const float4*)&rowbuf[wv][0];  // row base 16B-aligned (552*4B)
    #pragma unroll
    for (int i = 0; i < 3; ++i) {
        int q = lane + 64 * i;
        if (i < 2 || lane < 8) {                       // 64+64+8 = 136
            float4 w0 = rb[q], w1 = rb[q + 1], w2 = rb[q + 2];
            float f3 = w0.w, f4 = w1.x, f5 = w1.y, f6 = w1.z, f7 = w1.w;
            float f8 = w2.x, f9 = w2.y, f10 = w2.z;
            float a34 = fmaxf(f3, f4), a45 = fmaxf(f4, f5), a56 = fmaxf(f5, f6);
            float a67 = fmaxf(f6, f7), a78 = fmaxf(f7, f8), a89 = fmaxf(f8, f9);
            float4 o;
            o.x = fmaxf(fmaxf(a34, a56), f7);
            o.y = fmaxf(fmaxf(a45, a67), f8);
            o.z = fmaxf(fmaxf(a56, a78), f9);
            o.w = fmaxf(fmaxf(a67, a89), f10);
            *(float4*)&tmp5[wv][4 * q] = o;            // 16B-aligned (544*4B row stride)
        }
    }
    asm volatile("s_waitcnt lgkmcnt(0)" ::: "memory");
    __builtin_amdgcn_sched_barrier(0);

    // win35: out[4q+d] = max_k tmp5[4q+d+5k], k=0..6; 128 quad-tasks per row
    float* orow = rowmax + ((size_t)n * IMG_H + y) * IMG_W;
    const float4* t5 = (const float4*)&tmp5[wv][0];
    #pragma unroll
    for (int i = 0; i < 2; ++i) {
        int q = lane + 64 * i;
        float wf[36];                                  // static-indexed -> registers
        #pragma unroll
        for (int k = 0; k < 9; ++k) {
            float4 t = t5[q + k];
            wf[4 * k + 0] = t.x; wf[4 * k + 1] = t.y;
            wf[4 * k + 2] = t.z; wf[4 * k + 3] = t.w;
        }
        float4 o;
        #define M7(d) fmaxf(fmaxf(fmaxf(wf[(d)], wf[(d) + 5]), fmaxf(wf[(d) + 10], wf[(d) + 15])), \
                            fmaxf(fmaxf(wf[(d) + 20], wf[(d) + 25]), wf[(d) + 30]))
        o.x = M7(0); o.y = M7(1); o.z = M7(2); o.w = M7(3);
        #undef M7
        *(float4*)&orow[4 * q] = o;
    }
}

// -------- Pass 2: vertical win35 = win5 (shift ring) o win7-stride-5 (phase rings) ----
// Unchanged from R2/R4: float2 per thread, literal-indexed register rings, 512 blocks.
__global__ __launch_bounds__(256) void dc_colmax(const float* __restrict__ rowmax,
                                                 float* __restrict__ out) {
    __shared__ float wsum[4];
    const int b = blockIdx.x;            // n*16 + yt
    const int yt = b & 15;
    const int n = b >> 4;
    const int x0 = (int)threadIdx.x * 2; // columns x0, x0+1
    const int y0 = yt * YC2;
    const float2* col = (const float2*)(rowmax + (size_t)n * (IMG_H * IMG_W) + x0);

    float G0[5][6], G1[5][6];            // all accesses use literal [P][slot]
    #pragma unroll
    for (int p = 0; p < 5; ++p)
        #pragma unroll
        for (int k = 0; k < 6; ++k) { G0[p][k] = -INFINITY; G1[p][k] = -INFINITY; }

    float a1, a2, a3, a4;                // win5 shift ring, column x0
    float b1, b2, b3, b4;                // win5 shift ring, column x0+1
    float s = 0.0f;

    // prologue: rows gy = y0-17 .. y0-14
    {
        const int gy = y0 - 17;
        float2 v0 = ((unsigned)(gy + 0) < IMG_H) ? col[(size_t)(gy + 0) * (IMG_W / 2)]
                                                 : make_float2(-INFINITY, -INFINITY);
        float2 v1 = ((unsigned)(gy + 1) < IMG_H) ? col[(size_t)(gy + 1) * (IMG_W / 2)]
                                                 : make_float2(-INFINITY, -INFINITY);
        float2 v2 = ((unsigned)(gy + 2) < IMG_H) ? col[(size_t)(gy + 2) * (IMG_W / 2)]
                                                 : make_float2(-INFINITY, -INFINITY);
        float2 v3 = ((unsigned)(gy + 3) < IMG_H) ? col[(size_t)(gy + 3) * (IMG_W / 2)]
                                                 : make_float2(-INFINITY, -INFINITY);
        a1 = v0.x; a2 = v1.x; a3 = v2.x; a4 = v3.x;
        b1 = v0.y; b2 = v1.y; b3 = v2.y; b4 = v3.y;
    }

#define PUSH(P, J, DO_OUT)                                                              \
    {                                                                                   \
        const int gy_ = y0 - 13 + (J);                                                  \
        float2 v_ = ((unsigned)gy_ < IMG_H) ? col[(size_t)gy_ * (IMG_W / 2)]            \
                                            : make_float2(-INFINITY, -INFINITY);        \
        float gA_ = fmaxf(fmaxf(fmaxf(a1, a2), fmaxf(a3, a4)), v_.x);                   \
        float gB_ = fmaxf(fmaxf(fmaxf(b1, b2), fmaxf(b3, b4)), v_.y);                   \
        a1 = a2; a2 = a3; a3 = a4; a4 = v_.x;                                           \
        b1 = b2; b2 = b3; b3 = b4; b4 = v_.y;                                           \
        if (DO_OUT) {                                                                   \
            float oA_ = fmaxf(fmaxf(fmaxf(G0[P][0], G0[P][1]), fmaxf(G0[P][2], G0[P][3])), \
                              fmaxf(fmaxf(G0[P][4], G0[P][5]), gA_));                   \
            float oB_ = fmaxf(fmaxf(fmaxf(G1[P][0], G1[P][1]), fmaxf(G1[P][2], G1[P][3])), \
                              fmaxf(fmaxf(G1[P][4], G1[P][5]), gB_));                   \
            s += fabsf(oA_) + fabsf(oB_);                                               \
        }                                                                               \
        G0[P][0] = G0[P][1]; G0[P][1] = G0[P][2]; G0[P][2] = G0[P][3];                  \
        G0[P][3] = G0[P][4]; G0[P][4] = G0[P][5]; G0[P][5] = gA_;                       \
        G1[P][0] = G1[P][1]; G1[P][1] = G1[P][2]; G1[P][2] = G1[P][3];                  \
        G1[P][3] = G1[P][4]; G1[P][4] = G1[P][5]; G1[P][5] = gB_;                       \
    }

    // warm-up: J = 0..29, no outputs yet
    #pragma unroll
    for (int g5 = 0; g5 < 6; ++g5) {
        const int j0 = 5 * g5;
        PUSH(0, j0 + 0, 0) PUSH(1, j0 + 1, 0) PUSH(2, j0 + 2, 0)
        PUSH(3, j0 + 3, 0) PUSH(4, j0 + 4, 0)
    }
    // steady: J = 30..59 -> outputs y = 0..29
    #pragma unroll
    for (int g5 = 6; g5 < 12; ++g5) {
        const int j0 = 5 * g5;
        PUSH(0, j0 + 0, 1) PUSH(1, j0 + 1, 1) PUSH(2, j0 + 2, 1)
        PUSH(3, j0 + 3, 1) PUSH(4, j0 + 4, 1)
    }
    // tail: J = 60, 61 -> outputs y = 30, 31
    PUSH(0, 60, 1)
    PUSH(1, 61, 1)
#undef PUSH

    // wave64 reduce then cross-wave
    #pragma unroll
    for (int off = 32; off > 0; off >>= 1) s += __shfl_down(s, off);
    const int lane = (int)threadIdx.x & 63, wv = (int)threadIdx.x >> 6;
    if (lane == 0) wsum[wv] = s;
    __syncthreads();
    if (threadIdx.x == 0) {
        float t = wsum[0] + wsum[1] + wsum[2] + wsum[3];
        atomicAdd(out, t * (1.0f / ((float)NIMG * IMG_H * IMG_W)));
    }
}

extern "C" void kernel_launch(void* const* d_in, const int* in_sizes, int n_in,
                              void* d_out, int out_size, void* d_ws, size_t ws_size,
                              hipStream_t stream) {
    const float* img = (const float*)d_in[0];
    float* out = (float*)d_out;
    float* rowmax = (float*)d_ws;    // 32*512*512 floats = 33.5 MB scratch

    hipMemsetAsync(d_out, 0, sizeof(float), stream);
    dc_rowmax<<<NIMG * (IMG_H / R_ROWS), 256, 0, stream>>>(img, rowmax);
    dc_colmax<<<NIMG * 16, 256, 0, stream>>>(rowmax, out);
}